// Round 12
// baseline (22.369 us; speedup 1.0000x reference)
//
#include <hip/hip_runtime.h>
#include <hip/hip_bf16.h>

// RDF with minimum-image PBC + Gaussian smearing, N=2048 atoms, 100 bins.
//
// Round-12: occupancy experiment. r11 falsified the ticket theory (two-level
// ticket: no change). Cross-round decomposition (r5: replay overhead 1.5us;
// r2: finalize ~5us) shows the PAIR/HISTOGRAM phase has been ~14-15us since
// r4 under three different reduction structures, while issue-count models say
// ~3us. r2's PMC (VALUBusy 9.9%) says latency-bound; every variant since r4
// ran at most 16 waves/CU (4/SIMD) with a long dependent chain per iteration.
// This round: 512 blocks x 1024 threads = 2 blocks/CU x 16 waves = 32
// waves/CU (hardware max), __launch_bounds__(1024,8) to cap VGPRs at 64 so 8
// waves/SIMD are resident. Everything else identical to round 10:
//  - ONE LDS atomicAdd(1.0f) per pair into a FINE distance histogram
//    (17 sub-bins/bin, 4 private copies; integer counts in f32 -> exact,
//    order-independent); epilogue merges + convolves with a 103-tap
//    Gaussian (stride 17 coprime with 32 banks -> conflict-free).
//  - pairs with dist < 8 bin-units (~250 device-wide) take an exact
//    direct-smear path into bins 0..11 (tiny shell volumes amplify
//    quantization error there).
//  - publish: __hip_atomic_store(RELAXED, AGENT), 100 coalesced floats into
//    the block's own partials row (stride-112); rows fully overwritten
//    every call -> no zeroing, no memset node.
//  - flat modulo ticket (512 | 2^32 -> correct from any initial value,
//    never reset); __syncthreads drains vmem before the ticket RMW.
//  - last block: 51200 coalesced agent loads, fixed-order reduce ->
//    deterministic; normalize; d_out = [count(100) | bins(101) | rdf(100)].

#define N_ATOMS 2048
#define HALF    1024
#define NBINS   100
#define S_FINE  17          // fine sub-bins per coarse bin (coprime with 32)
#define FBINS   1744        // > 102.5 * 17 = 1742.5
#define NCOPY   4           // private fine-histogram copies
#define TAPS    103         // 2*3*17 + 1  (window +-3 bin widths)
#define NDIR    12          // exact direct-path coarse bins 0..11
#define TLOW    8.0f        // bin-units: below this, take the exact path
#define NBLOCKS 512         // power of 2: modulo ticket needs NBLOCKS | 2^32
#define NTHREADS 1024
#define ROWS_PB 4           // N_ATOMS / NBLOCKS
#define PADB    112         // padded row stride for publish slots

__global__ __launch_bounds__(1024, 8) void rdf_fused(
    const float* __restrict__ xyz,
    const float* __restrict__ cell,
    const float* __restrict__ offsets,
    const float* __restrict__ bins,
    float* __restrict__ out,
    float* __restrict__ partials,   // [NBLOCKS][PADB], store-overwritten
    unsigned* __restrict__ ticket)  // never reset (modulo trick)
{
    __shared__ float fine[NCOPY][FBINS];   // private fine histograms
    __shared__ float wtab[TAPS];           // Gaussian taps
    __shared__ float conv[NBINS][8];       // conv partials / tail reduce
    __shared__ float cd[16];               // exact direct-path coarse bins
    __shared__ float ssum[2];
    __shared__ unsigned stick;

    const int tid = threadIdx.x;
    const int bid = blockIdx.x;

    for (int a = tid; a < NCOPY * FBINS; a += NTHREADS)
        (&fine[0][0])[a] = 0.0f;
    if (tid < 16)   cd[tid] = 0.0f;
    if (tid < TAPS) {
        const float u = ((float)tid - 50.5f) * (1.0f / (float)S_FINE);
        wtab[tid] = __expf(-0.5f * u * u);
    }
    __syncthreads();

    const float cx = cell[0], cy = cell[1], cz = cell[2];
    const float hcx = 0.5f * cx, hcy = 0.5f * cy, hcz = 0.5f * cz;

    const float width = offsets[1] - offsets[0];   // 7.5/99
    const float invw  = 1.0f / width;
    // beyond 102.5 bin-units no bin k<=99 lies within the +-3w window
    const float cutd   = 102.5f * width;           // 7.765 < CUTOFF_B = 8.0
    const float cut2   = cutd * cutd;

    float* const myfine = fine[tid >> 8];          // 4 waves per copy

    // ---- main loop: 4 rows per block, one 1024-wide j-sweep per row ----
    const int row0 = bid << 2;
    #pragma unroll
    for (int r = 0; r < ROWS_PB; ++r) {
        const int i = row0 + r;                    // wave-uniform
        const float xi = xyz[3 * i + 0];           // scalar loads
        const float yi = xyz[3 * i + 1];
        const float zi = xyz[3 * i + 2];
        if (tid == HALF - 1 && i >= HALF) continue; // dedup N/2 diagonal
        const int j = (i + 1 + tid) & (N_ATOMS - 1);

        float dx = xyz[3 * j + 0] - xi;            // coalesced, L1-resident
        float dy = xyz[3 * j + 1] - yi;
        float dz = xyz[3 * j + 2] - zi;
        // minimum-image wrap (matches reference shift semantics)
        dx += (dx >= hcx) ? -cx : ((dx < -hcx) ? cx : 0.0f);
        dy += (dy >= hcy) ? -cy : ((dy < -hcy) ? cy : 0.0f);
        dz += (dz >= hcz) ? -cz : ((dz < -hcz) ? cz : 0.0f);

        const float dsq = dx * dx + dy * dy + dz * dz;
        if (dsq < cut2 && dsq != 0.0f) {
            const float tu = sqrtf(dsq) * invw;    // dist in bin units
            if (tu >= TLOW) {
                // ONE LDS atomic/pair; lanes scatter over 1744 bins
                atomicAdd(&myfine[(int)(tu * (float)S_FINE)], 1.0f);
            } else {
                // exact path for low bins (~250 pairs device-wide)
                int khi = (int)tu + 4; if (khi > NDIR - 1) khi = NDIR - 1;
                for (int k = 0; k <= khi; ++k) {
                    const float e = tu - (float)k;
                    atomicAdd(&cd[k], __expf(-0.5f * e * e));
                }
            }
        }
    }

    __syncthreads();

    // merge the 4 copies into copy 0 (stride-1, conflict-free)
    for (int a = tid; a < FBINS; a += NTHREADS)
        fine[0][a] += fine[1][a] + fine[2][a] + fine[3][a];
    __syncthreads();

    // coarse[k] = sum_d wtab[d+51] * fine[17k+d], d in [-51,51]
    // 400 threads: k = t>>2, chunk c = t&3 (26/26/26/25 taps); stride-17
    // fine reads are bank-conflict free (gcd(17,32)=1)
    if (tid < 400) {
        const int k = tid >> 2;
        const int c = tid & 3;
        const int m0 = c * 26;
        const int mcnt = (c == 3) ? 25 : 26;
        float s = 0.0f;
        for (int mm = 0; mm < mcnt; ++mm) {
            const int m = m0 + mm;
            const int f = S_FINE * k + m - 51;     // max 17*99+51 = 1734
            if (f >= 0) s += wtab[m] * fine[0][f];
        }
        conv[k][c] = s;
    }
    __syncthreads();

    // ---- publish: coherent coalesced stores into this block's own row ----
    if (tid < NBINS) {
        float raw = conv[tid][0] + conv[tid][1] + conv[tid][2] + conv[tid][3];
        if (tid < NDIR) raw += cd[tid];
        __hip_atomic_store(&partials[bid * PADB + tid], raw,
                           __ATOMIC_RELAXED, __HIP_MEMORY_SCOPE_AGENT);
    }

    // barrier drains each wave's outstanding vmem (stores complete at the
    // coherence point) before thread 0's ticket RMW
    __syncthreads();
    if (tid == 0)
        stick = __hip_atomic_fetch_add(ticket, 1u, __ATOMIC_ACQ_REL,
                                       __HIP_MEMORY_SCOPE_AGENT);
    __syncthreads();
    if ((stick & (NBLOCKS - 1)) != (NBLOCKS - 1)) return;

    // ---- last-arriving block: coherent coalesced read-back ----
    // thread t: bin b = t&127, chunk c = t>>7; sums 64 blocks, fixed order.
    {
        const int b = tid & 127;
        const int c = tid >> 7;
        if (b < NBINS) {
            float s = 0.0f;
            #pragma unroll 8
            for (int q = 0; q < NBLOCKS / 8; ++q) {
                const int blk = c * (NBLOCKS / 8) + q;
                s += __hip_atomic_load(&partials[blk * PADB + b],
                                       __ATOMIC_RELAXED,
                                       __HIP_MEMORY_SCOPE_AGENT);
            }
            conv[b][c] = s;
        }
    }
    __syncthreads();

    float raw = 0.0f;
    if (tid < NBINS) {
        #pragma unroll
        for (int c = 0; c < 8; ++c) raw += conv[tid][c];
    }
    if (tid < 128) {
        float v = raw;
        #pragma unroll
        for (int o = 32; o > 0; o >>= 1) v += __shfl_down(v, o);
        if ((tid & 63) == 0) ssum[tid >> 6] = v;
    }
    __syncthreads();
    const float S = ssum[0] + ssum[1];

    if (tid < NBINS) {
        const float cnt = raw / S;
        out[tid] = cnt;                                // count
        const float b0 = bins[tid], b1 = bins[tid + 1];
        const float R  = bins[NBINS];                  // R_END = 7.5
        // rdf = cnt / (vol_bin / V) = cnt * R^3 / (b1^3 - b0^3)  (4pi/3 cancels)
        out[201 + tid] = cnt * (R * R * R) / (b1 * b1 * b1 - b0 * b0 * b0);
    }
    if (tid < NBINS + 1) {
        out[100 + tid] = bins[tid];                    // bins passthrough
    }
}

extern "C" void kernel_launch(void* const* d_in, const int* in_sizes, int n_in,
                              void* d_out, int out_size, void* d_ws, size_t ws_size,
                              hipStream_t stream) {
    const float* xyz     = (const float*)d_in[0];
    const float* cell    = (const float*)d_in[1];
    const float* bins    = (const float*)d_in[2];
    const float* offsets = (const float*)d_in[3];
    float* out = (float*)d_out;

    float*    partials = (float*)d_ws;   // NBLOCKS*PADB floats, overwritten
    unsigned* ticket   = (unsigned*)((char*)d_ws +
                                     (size_t)NBLOCKS * PADB * sizeof(float));

    // single graph node: no memset, no second kernel
    rdf_fused<<<NBLOCKS, NTHREADS, 0, stream>>>(xyz, cell, offsets, bins, out,
                                                partials, ticket);
}

// Round 13
// 17.241 us; speedup vs baseline: 1.2974x; 1.2974x over previous
//
#include <hip/hip_runtime.h>
#include <hip/hip_bf16.h>

// RDF with minimum-image PBC + Gaussian smearing, N=2048 atoms, 100 bins.
//
// Round-13: r10 config exactly (best: 17.2us), ONE variable changed —
// the fine histogram uses UNSIGNED atomicAdd(p,1u) (native ds_add_u32)
// instead of float atomicAdd(p,1.0f). Cross-round fit (r2: 23M LDS f32
// atomics <-> 65.8us; r4+: 2M <-> ~13us histogram phase, invariant under
// thread/wave config changes r8/r10/r12) gives ~2.8us per M f32-atomics —
// the f32 LDS RMW is the serial resource. Counts are integers; u32 atomic
// is single-pass. Converted to float in the conv (exact, counts << 2^24).
//
// Structure (= r10): 256 blocks x 1024 threads, block owns 8 rows of the
// cyclic upper-triangle enumeration (j=(i+1+t) mod N, t in [0,1024); one
// predicate dedups the d==N/2 diagonal; x2 pair weight cancels in count
// normalization). i wave-uniform -> scalar i-loads; j-loads coalesced,
// L1-resident (xyz=24KB). ONE LDS atomic per pair into a FINE distance
// histogram (17 sub-bins/bin, 4 private copies; integer counts -> exact,
// order-independent). Epilogue merges copies + convolves with a 103-tap
// Gaussian (stride 17 coprime with 32 banks -> conflict-free). Pairs with
// dist < 8 bin-units (~250 device-wide) take an exact f32 direct-smear
// path into bins 0..11 (tiny shell volumes amplify quantization error).
//  - publish: __hip_atomic_store(RELAXED, AGENT), 100 coalesced floats
//    into the block's own partials row (stride-112); rows fully
//    overwritten every call -> no zeroing, no memset node.
//  - flat modulo ticket (256 | 2^32 -> correct from any initial value,
//    never reset); __syncthreads drains vmem before the ticket RMW.
//  - last block: coalesced agent loads, fixed-order reduce ->
//    deterministic; normalize; d_out = [count(100)|bins(101)|rdf(100)].

#define N_ATOMS 2048
#define HALF    1024
#define NBINS   100
#define S_FINE  17          // fine sub-bins per coarse bin (coprime with 32)
#define FBINS   1744        // > 102.5 * 17 = 1742.5
#define NCOPY   4           // private fine-histogram copies
#define TAPS    103         // 2*3*17 + 1  (window +-3 bin widths)
#define NDIR    12          // exact direct-path coarse bins 0..11
#define TLOW    8.0f        // bin-units: below this, take the exact path
#define NBLOCKS 256         // power of 2: modulo ticket needs NBLOCKS | 2^32
#define NTHREADS 1024
#define ROWS_PB 8           // N_ATOMS / NBLOCKS
#define PADB    112         // padded row stride for publish slots

__global__ __launch_bounds__(1024) void rdf_fused(
    const float* __restrict__ xyz,
    const float* __restrict__ cell,
    const float* __restrict__ offsets,
    const float* __restrict__ bins,
    float* __restrict__ out,
    float* __restrict__ partials,   // [NBLOCKS][PADB], store-overwritten
    unsigned* __restrict__ ticket)  // never reset (modulo trick)
{
    __shared__ unsigned fine[NCOPY][FBINS];  // private fine histograms (u32)
    __shared__ float wtab[TAPS];             // Gaussian taps
    __shared__ float conv[NBINS][8];         // conv partials / tail reduce
    __shared__ float cd[16];                 // exact direct-path coarse bins
    __shared__ float ssum[2];
    __shared__ unsigned stick;

    const int tid = threadIdx.x;
    const int bid = blockIdx.x;

    for (int a = tid; a < NCOPY * FBINS; a += NTHREADS)
        (&fine[0][0])[a] = 0u;
    if (tid < 16)   cd[tid] = 0.0f;
    if (tid < TAPS) {
        const float u = ((float)tid - 50.5f) * (1.0f / (float)S_FINE);
        wtab[tid] = __expf(-0.5f * u * u);
    }
    __syncthreads();

    const float cx = cell[0], cy = cell[1], cz = cell[2];
    const float hcx = 0.5f * cx, hcy = 0.5f * cy, hcz = 0.5f * cz;

    const float width = offsets[1] - offsets[0];   // 7.5/99
    const float invw  = 1.0f / width;
    // beyond 102.5 bin-units no bin k<=99 lies within the +-3w window
    const float cutd   = 102.5f * width;           // 7.765 < CUTOFF_B = 8.0
    const float cut2   = cutd * cutd;

    unsigned* const myfine = fine[tid >> 8];       // 4 waves per copy

    // ---- main loop: 8 rows per block, one 1024-wide j-sweep per row ----
    const int row0 = bid << 3;
    #pragma unroll
    for (int r = 0; r < ROWS_PB; ++r) {
        const int i = row0 + r;                    // wave-uniform
        const float xi = xyz[3 * i + 0];           // scalar loads
        const float yi = xyz[3 * i + 1];
        const float zi = xyz[3 * i + 2];
        if (tid == HALF - 1 && i >= HALF) continue; // dedup N/2 diagonal
        const int j = (i + 1 + tid) & (N_ATOMS - 1);

        float dx = xyz[3 * j + 0] - xi;            // coalesced, L1-resident
        float dy = xyz[3 * j + 1] - yi;
        float dz = xyz[3 * j + 2] - zi;
        // minimum-image wrap (matches reference shift semantics)
        dx += (dx >= hcx) ? -cx : ((dx < -hcx) ? cx : 0.0f);
        dy += (dy >= hcy) ? -cy : ((dy < -hcy) ? cy : 0.0f);
        dz += (dz >= hcz) ? -cz : ((dz < -hcz) ? cz : 0.0f);

        const float dsq = dx * dx + dy * dy + dz * dz;
        if (dsq < cut2 && dsq != 0.0f) {
            const float tu = sqrtf(dsq) * invw;    // dist in bin units
            if (tu >= TLOW) {
                // ONE native u32 LDS atomic/pair; lanes scatter over 1744
                atomicAdd(&myfine[(int)(tu * (float)S_FINE)], 1u);
            } else {
                // exact f32 path for low bins (~250 pairs device-wide)
                int khi = (int)tu + 4; if (khi > NDIR - 1) khi = NDIR - 1;
                for (int k = 0; k <= khi; ++k) {
                    const float e = tu - (float)k;
                    atomicAdd(&cd[k], __expf(-0.5f * e * e));
                }
            }
        }
    }

    __syncthreads();

    // merge the 4 copies into copy 0 (stride-1, conflict-free, int adds)
    for (int a = tid; a < FBINS; a += NTHREADS)
        fine[0][a] += fine[1][a] + fine[2][a] + fine[3][a];
    __syncthreads();

    // coarse[k] = sum_d wtab[d+51] * fine[17k+d], d in [-51,51]
    // 400 threads: k = t>>2, chunk c = t&3 (26/26/26/25 taps); stride-17
    // fine reads are bank-conflict free (gcd(17,32)=1)
    if (tid < 400) {
        const int k = tid >> 2;
        const int c = tid & 3;
        const int m0 = c * 26;
        const int mcnt = (c == 3) ? 25 : 26;
        float s = 0.0f;
        for (int mm = 0; mm < mcnt; ++mm) {
            const int m = m0 + mm;
            const int f = S_FINE * k + m - 51;     // max 17*99+51 = 1734
            if (f >= 0) s += wtab[m] * (float)fine[0][f];  // exact: < 2^24
        }
        conv[k][c] = s;
    }
    __syncthreads();

    // ---- publish: coherent coalesced stores into this block's own row ----
    if (tid < NBINS) {
        float raw = conv[tid][0] + conv[tid][1] + conv[tid][2] + conv[tid][3];
        if (tid < NDIR) raw += cd[tid];
        __hip_atomic_store(&partials[bid * PADB + tid], raw,
                           __ATOMIC_RELAXED, __HIP_MEMORY_SCOPE_AGENT);
    }

    // barrier drains each wave's outstanding vmem (stores complete at the
    // coherence point) before thread 0's ticket RMW
    __syncthreads();
    if (tid == 0)
        stick = __hip_atomic_fetch_add(ticket, 1u, __ATOMIC_ACQ_REL,
                                       __HIP_MEMORY_SCOPE_AGENT);
    __syncthreads();
    if ((stick & (NBLOCKS - 1)) != (NBLOCKS - 1)) return;

    // ---- last-arriving block: coherent coalesced read-back ----
    // thread t: bin b = t&127, chunk c = t>>7; sums 32 blocks, fixed order.
    {
        const int b = tid & 127;
        const int c = tid >> 7;
        if (b < NBINS) {
            float s = 0.0f;
            #pragma unroll 8
            for (int q = 0; q < NBLOCKS / 8; ++q) {
                const int blk = c * (NBLOCKS / 8) + q;
                s += __hip_atomic_load(&partials[blk * PADB + b],
                                       __ATOMIC_RELAXED,
                                       __HIP_MEMORY_SCOPE_AGENT);
            }
            conv[b][c] = s;
        }
    }
    __syncthreads();

    float raw = 0.0f;
    if (tid < NBINS) {
        #pragma unroll
        for (int c = 0; c < 8; ++c) raw += conv[tid][c];
    }
    if (tid < 128) {
        float v = raw;
        #pragma unroll
        for (int o = 32; o > 0; o >>= 1) v += __shfl_down(v, o);
        if ((tid & 63) == 0) ssum[tid >> 6] = v;
    }
    __syncthreads();
    const float S = ssum[0] + ssum[1];

    if (tid < NBINS) {
        const float cnt = raw / S;
        out[tid] = cnt;                                // count
        const float b0 = bins[tid], b1 = bins[tid + 1];
        const float R  = bins[NBINS];                  // R_END = 7.5
        // rdf = cnt / (vol_bin / V) = cnt * R^3 / (b1^3 - b0^3)  (4pi/3 cancels)
        out[201 + tid] = cnt * (R * R * R) / (b1 * b1 * b1 - b0 * b0 * b0);
    }
    if (tid < NBINS + 1) {
        out[100 + tid] = bins[tid];                    // bins passthrough
    }
}

extern "C" void kernel_launch(void* const* d_in, const int* in_sizes, int n_in,
                              void* d_out, int out_size, void* d_ws, size_t ws_size,
                              hipStream_t stream) {
    const float* xyz     = (const float*)d_in[0];
    const float* cell    = (const float*)d_in[1];
    const float* bins    = (const float*)d_in[2];
    const float* offsets = (const float*)d_in[3];
    float* out = (float*)d_out;

    float*    partials = (float*)d_ws;   // NBLOCKS*PADB floats, overwritten
    unsigned* ticket   = (unsigned*)((char*)d_ws +
                                     (size_t)NBLOCKS * PADB * sizeof(float));

    // single graph node: no memset, no second kernel
    rdf_fused<<<NBLOCKS, NTHREADS, 0, stream>>>(xyz, cell, offsets, bins, out,
                                                partials, ticket);
}

// Round 15
// 15.008 us; speedup vs baseline: 1.4905x; 1.1488x over previous
//
#include <hip/hip_runtime.h>
#include <hip/hip_bf16.h>

// RDF with minimum-image PBC + Gaussian smearing, N=2048 atoms, 100 bins.
//
// Round-15: fused single dispatch; handoff rebuilt from the r14 failure
// analysis. r14 (relaxed ticket + plain agent stores/loads) failed ONLY on
// low-r rdf bins -> a few blocks' partials were invisible: relaxed agent
// plain stores can sit dirty in the publisher's (non-coherent) XCD L2, and
// relaxed agent loads can hit the reader's stale L2. The ACQ_REL ticket of
// r10-r13 fixed that via per-RMW L2 writeback+invalidate — which is also
// the ~13us residual (20-50ns x 256, fits r11/r12 deltas). r9 passed with
// ALL-RMW traffic because RMWs execute at the coherence point (IF).
// Recipe here (validated pieces only):
//  - publish: atomicExch (RMW at IF, r9-validated; no release needed);
//    slots fully overwritten every call -> no zeroing, no memset node.
//  - tickets: two-level (16 subs x 16 + 16-arrival master, 256B apart),
//    ALL RELAXED (RMWs at IF; modulo trick -> correct from any poison
//    value, never reset).
//  - winner: ONE acquire RMW (single buffer_inv) + readback via
//    SYSTEM-scope relaxed loads (sc0+sc1 bypass L1&L2 -> read at IF).
//    256 cache-maintenance ops -> 1.
//
// Structure otherwise = r13 (best passing, 17.2us): 256 blocks x 1024
// threads; block owns 8 rows of the cyclic upper-triangle enumeration
// (j=(i+1+t) mod N; one predicate dedups the d==N/2 diagonal; x2 pair
// weight cancels in count normalization). i wave-uniform -> scalar
// i-loads; j-loads coalesced, L1-resident (xyz=24KB). ONE u32 LDS atomic
// per pair into a FINE distance histogram (17 sub-bins/bin, 4 private
// copies; integer counts -> exact, order-independent). Epilogue merges
// copies + convolves with a 103-tap Gaussian (stride 17 coprime with 32
// banks -> conflict-free). Pairs with dist < 8 bin-units (~250
// device-wide) take an exact f32 direct-smear path into bins 0..11 (tiny
// shell volumes amplify quantization error there). Winner reduces in
// fixed order -> deterministic; d_out = [count(100)|bins(101)|rdf(100)].

#define N_ATOMS 2048
#define HALF    1024
#define NBINS   100
#define S_FINE  17          // fine sub-bins per coarse bin (coprime with 32)
#define FBINS   1744        // > 102.5 * 17 = 1742.5
#define NCOPY   4           // private fine-histogram copies
#define TAPS    103         // 2*3*17 + 1  (window +-3 bin widths)
#define NDIR    12          // exact direct-path coarse bins 0..11
#define TLOW    8.0f        // bin-units: below this, take the exact path
#define NBLOCKS 256         // power of 2: modulo tickets need divisors of 2^32
#define NTHREADS 1024
#define ROWS_PB 8           // N_ATOMS / NBLOCKS
#define PADB    112         // padded row stride for publish slots
#define NSUB    16          // sub-tickets; NBLOCKS/NSUB = 16 arrivals each
#define TSTRIDE 64          // words between ticket slots (256B apart)

__global__ __launch_bounds__(1024) void rdf_fused(
    const float* __restrict__ xyz,
    const float* __restrict__ cell,
    const float* __restrict__ offsets,
    const float* __restrict__ bins,
    float* __restrict__ out,
    float* __restrict__ partials,   // [NBLOCKS][PADB], exch-overwritten
    unsigned* __restrict__ tickets) // NSUB subs + 1 master, never reset
{
    __shared__ unsigned fine[NCOPY][FBINS];  // private fine histograms (u32)
    __shared__ float wtab[TAPS];             // Gaussian taps
    __shared__ float conv[NBINS][8];         // conv partials / tail reduce
    __shared__ float cd[16];                 // exact direct-path coarse bins
    __shared__ float ssum[2];
    __shared__ unsigned stick;

    const int tid = threadIdx.x;
    const int bid = blockIdx.x;

    for (int a = tid; a < NCOPY * FBINS; a += NTHREADS)
        (&fine[0][0])[a] = 0u;
    if (tid < 16)   cd[tid] = 0.0f;
    if (tid < TAPS) {
        const float u = ((float)tid - 50.5f) * (1.0f / (float)S_FINE);
        wtab[tid] = __expf(-0.5f * u * u);
    }
    __syncthreads();

    const float cx = cell[0], cy = cell[1], cz = cell[2];
    const float hcx = 0.5f * cx, hcy = 0.5f * cy, hcz = 0.5f * cz;

    const float width = offsets[1] - offsets[0];   // 7.5/99
    const float invw  = 1.0f / width;
    // beyond 102.5 bin-units no bin k<=99 lies within the +-3w window
    const float cutd   = 102.5f * width;           // 7.765 < CUTOFF_B = 8.0
    const float cut2   = cutd * cutd;

    unsigned* const myfine = fine[tid >> 8];       // 4 waves per copy

    // ---- main loop: 8 rows per block, one 1024-wide j-sweep per row ----
    const int row0 = bid << 3;
    #pragma unroll
    for (int r = 0; r < ROWS_PB; ++r) {
        const int i = row0 + r;                    // wave-uniform
        const float xi = xyz[3 * i + 0];           // scalar loads
        const float yi = xyz[3 * i + 1];
        const float zi = xyz[3 * i + 2];
        if (tid == HALF - 1 && i >= HALF) continue; // dedup N/2 diagonal
        const int j = (i + 1 + tid) & (N_ATOMS - 1);

        float dx = xyz[3 * j + 0] - xi;            // coalesced, L1-resident
        float dy = xyz[3 * j + 1] - yi;
        float dz = xyz[3 * j + 2] - zi;
        // minimum-image wrap (matches reference shift semantics)
        dx += (dx >= hcx) ? -cx : ((dx < -hcx) ? cx : 0.0f);
        dy += (dy >= hcy) ? -cy : ((dy < -hcy) ? cy : 0.0f);
        dz += (dz >= hcz) ? -cz : ((dz < -hcz) ? cz : 0.0f);

        const float dsq = dx * dx + dy * dy + dz * dz;
        if (dsq < cut2 && dsq != 0.0f) {
            const float tu = sqrtf(dsq) * invw;    // dist in bin units
            if (tu >= TLOW) {
                // ONE native u32 LDS atomic/pair; lanes scatter over 1744
                atomicAdd(&myfine[(int)(tu * (float)S_FINE)], 1u);
            } else {
                // exact f32 path for low bins (~250 pairs device-wide)
                int khi = (int)tu + 4; if (khi > NDIR - 1) khi = NDIR - 1;
                for (int k = 0; k <= khi; ++k) {
                    const float e = tu - (float)k;
                    atomicAdd(&cd[k], __expf(-0.5f * e * e));
                }
            }
        }
    }

    __syncthreads();

    // merge the 4 copies into copy 0 (stride-1, conflict-free, int adds)
    for (int a = tid; a < FBINS; a += NTHREADS)
        fine[0][a] += fine[1][a] + fine[2][a] + fine[3][a];
    __syncthreads();

    // coarse[k] = sum_d wtab[d+51] * fine[17k+d], d in [-51,51]
    // 400 threads: k = t>>2, chunk c = t&3 (26/26/26/25 taps); stride-17
    // fine reads are bank-conflict free (gcd(17,32)=1)
    if (tid < 400) {
        const int k = tid >> 2;
        const int c = tid & 3;
        const int m0 = c * 26;
        const int mcnt = (c == 3) ? 25 : 26;
        float s = 0.0f;
        for (int mm = 0; mm < mcnt; ++mm) {
            const int m = m0 + mm;
            const int f = S_FINE * k + m - 51;     // max 17*99+51 = 1734
            if (f >= 0) s += wtab[m] * (float)fine[0][f];  // exact: < 2^24
        }
        conv[k][c] = s;
    }
    __syncthreads();

    // ---- publish: RMW (atomicExch) into per-block-unique slots.
    // RMWs execute at the coherence point (IF) -> no release needed
    // (r9-validated). Distinct addresses -> no contention.
    if (tid < NBINS) {
        float raw = conv[tid][0] + conv[tid][1] + conv[tid][2] + conv[tid][3];
        if (tid < NDIR) raw += cd[tid];
        atomicExch(&partials[bid * PADB + tid], raw);
    }

    // barrier drains each wave's outstanding vmem (the exchanges are
    // performed at IF) before thread 0's ticket RMWs
    __syncthreads();
    if (tid == 0) {
        unsigned last = 0u;
        const unsigned so = __hip_atomic_fetch_add(
            &tickets[(bid & (NSUB - 1)) * TSTRIDE], 1u,
            __ATOMIC_RELAXED, __HIP_MEMORY_SCOPE_AGENT);
        if ((so & (NBLOCKS / NSUB - 1)) == (NBLOCKS / NSUB - 1)) {
            // sub-group's last arrival; its RMW completed before this one
            const unsigned mo = __hip_atomic_fetch_add(
                &tickets[NSUB * TSTRIDE], 1u,
                __ATOMIC_RELAXED, __HIP_MEMORY_SCOPE_AGENT);
            last = ((mo & (NSUB - 1)) == (NSUB - 1)) ? 1u : 0u;
        }
        if (last) {
            // ONE acquire (single buffer_inv) for the whole handoff
            __hip_atomic_fetch_add(&tickets[NSUB * TSTRIDE], 0u,
                                   __ATOMIC_ACQUIRE, __HIP_MEMORY_SCOPE_AGENT);
        }
        stick = last;
    }
    __syncthreads();
    if (!stick) return;

    // ---- winner: readback via SYSTEM-scope relaxed loads (sc0+sc1 ->
    // bypass L1 and L2, read at IF where the exchanges landed).
    // thread t: bin b = t&127, chunk c = t>>7; sums 32 blocks, fixed order.
    {
        const int b = tid & 127;
        const int c = tid >> 7;
        if (b < NBINS) {
            float s = 0.0f;
            #pragma unroll 8
            for (int q = 0; q < NBLOCKS / 8; ++q) {
                const int blk = c * (NBLOCKS / 8) + q;
                s += __hip_atomic_load(&partials[blk * PADB + b],
                                       __ATOMIC_RELAXED,
                                       __HIP_MEMORY_SCOPE_SYSTEM);
            }
            conv[b][c] = s;
        }
    }
    __syncthreads();

    float raw = 0.0f;
    if (tid < NBINS) {
        #pragma unroll
        for (int c = 0; c < 8; ++c) raw += conv[tid][c];
    }
    if (tid < 128) {
        float v = raw;
        #pragma unroll
        for (int o = 32; o > 0; o >>= 1) v += __shfl_down(v, o);
        if ((tid & 63) == 0) ssum[tid >> 6] = v;
    }
    __syncthreads();
    const float S = ssum[0] + ssum[1];

    if (tid < NBINS) {
        const float cnt = raw / S;
        out[tid] = cnt;                                // count
        const float b0 = bins[tid], b1 = bins[tid + 1];
        const float R  = bins[NBINS];                  // R_END = 7.5
        // rdf = cnt / (vol_bin / V) = cnt * R^3 / (b1^3 - b0^3)  (4pi/3 cancels)
        out[201 + tid] = cnt * (R * R * R) / (b1 * b1 * b1 - b0 * b0 * b0);
    }
    if (tid < NBINS + 1) {
        out[100 + tid] = bins[tid];                    // bins passthrough
    }
}

extern "C" void kernel_launch(void* const* d_in, const int* in_sizes, int n_in,
                              void* d_out, int out_size, void* d_ws, size_t ws_size,
                              hipStream_t stream) {
    const float* xyz     = (const float*)d_in[0];
    const float* cell    = (const float*)d_in[1];
    const float* bins    = (const float*)d_in[2];
    const float* offsets = (const float*)d_in[3];
    float* out = (float*)d_out;

    float*    partials = (float*)d_ws;   // NBLOCKS*PADB floats, exch-overwritten
    unsigned* tickets  = (unsigned*)((char*)d_ws +
                                     (size_t)NBLOCKS * PADB * sizeof(float));

    // single graph node: no memset, no second kernel
    rdf_fused<<<NBLOCKS, NTHREADS, 0, stream>>>(xyz, cell, offsets, bins, out,
                                                partials, tickets);
}